// Round 1
// baseline (148.416 us; speedup 1.0000x reference)
//
#include <hip/hip_runtime.h>
#include <math.h>

// Problem constants
#define BB 64
#define CC 1000
#define FF 2048
#define KB 32

// ws layout (float offsets)
#define OFF_SPART 0              // [16][64][1000]
#define OFF_HPART 1024000        // [16][64][1000]
#define OFF_SELP  2048000        // [8][64][2048]
#define OFF_MEMP  3096576        // [8][64][2048]
#define OFF_LOGP  4145152        // [16][64][1000]
#define OFF_V     5169152        // [64][1000]
#define OFF_FEAT  5233152        // [64][2048]
#define OFF_CN2   5364224        // [1000]
#define OFF_WINV  5365224        // [1000]
#define OFF_XN2   5366224        // [64]
#define OFF_REACH 5366288        // [64]
#define OFF_SFAC  5366352        // [64]

// Stage rows [rowBase..rowBase+64) x k-cols [k0..k0+KB) of row-major-K matrix M
// into LDS transposed: Ts[kk][r]. Zero-pads OOB rows / k.
__device__ __forceinline__ void stage_bt(const float* __restrict__ M, int ldK, int rowBase,
                                         int nrows, int k0, int kmax, float* Ts, int t) {
  int r = t >> 2;       // 0..63
  int q = t & 3;        // 0..3 -> 8 k's each
  int grow = rowBase + r;
  bool rok = grow < nrows;
  const float* src = M + (size_t)grow * ldK + k0 + q * 8;
#pragma unroll
  for (int h = 0; h < 2; ++h) {
    int kbase = q * 8 + h * 4;
    float4 v = make_float4(0.f, 0.f, 0.f, 0.f);
    if (rok) {
      if (k0 + kbase + 3 < kmax) {
        v = *(const float4*)(src + h * 4);
      } else {
#pragma unroll
        for (int j = 0; j < 4; ++j) {
          int kk = k0 + kbase + j;
          if (kk < kmax) ((float*)&v)[j] = src[h * 4 + j];
        }
      }
    }
    Ts[(kbase + 0) * 64 + r] = v.x;
    Ts[(kbase + 1) * 64 + r] = v.y;
    Ts[(kbase + 2) * 64 + r] = v.z;
    Ts[(kbase + 3) * 64 + r] = v.w;
  }
}

// Stage k-rows [k0..k0+KB) x n-cols [n0..n0+64) of row-major-N matrix M into
// LDS natural: Ts[kk][n]. Zero-pads OOB k rows. n assumed in-range.
__device__ __forceinline__ void stage_bn(const float* __restrict__ M, int ldN, int k0, int kmax,
                                         int n0, float* Ts, int t) {
  int kk = t >> 3;          // 0..31
  int c8 = (t & 7) * 8;     // 0,8,..,56
  int gk = k0 + kk;
  const float* src = M + (size_t)gk * ldN + n0 + c8;
#pragma unroll
  for (int h = 0; h < 2; ++h) {
    float4 v = make_float4(0.f, 0.f, 0.f, 0.f);
    if (gk < kmax) v = *(const float4*)(src + h * 4);
    *(float4*)(Ts + kk * 64 + c8 + h * 4) = v;
  }
}

// Phase 1: blocks 0..255   : dual GEMM S = x@cent^T, H = x@W_hall^T  (16 tiles x 16 ksplits, chunk 128)
//          blocks 256..511 : GEMM selpre = x@W_sel^T                 (32 tiles x 8 ksplits, chunk 256)
//          blocks 512..1027: row norms (cnorm2, winv, xnorm2), 4 rows/block (one per wave)
__global__ __launch_bounds__(256) void k_phase1(
    const float* __restrict__ x, const float* __restrict__ cent,
    const float* __restrict__ whall, const float* __restrict__ wsel,
    const float* __restrict__ wcos, float* __restrict__ ws) {
  __shared__ float lds[3 * KB * 64];
  float* As = lds;
  float* B1s = lds + KB * 64;
  float* B2s = lds + 2 * KB * 64;
  int bx = blockIdx.x;
  int t = threadIdx.x;
  int tx = t & 15, ty = t >> 4;

  if (bx < 256) {
    int tile = bx & 15, ks = bx >> 4;
    int n0 = tile * 64;
    float accS[4][4] = {{0.f}}, accH[4][4] = {{0.f}};
    for (int kc = 0; kc < 128; kc += KB) {
      int k0 = ks * 128 + kc;
      __syncthreads();
      stage_bt(x, FF, 0, BB, k0, FF, As, t);
      stage_bt(cent, FF, n0, CC, k0, FF, B1s, t);
      stage_bt(whall, FF, n0, CC, k0, FF, B2s, t);
      __syncthreads();
#pragma unroll 8
      for (int kk = 0; kk < KB; ++kk) {
        float4 av = *(const float4*)(As + kk * 64 + ty * 4);
        float4 b1 = *(const float4*)(B1s + kk * 64 + tx * 4);
        float4 b2 = *(const float4*)(B2s + kk * 64 + tx * 4);
        float a[4] = {av.x, av.y, av.z, av.w};
        float p[4] = {b1.x, b1.y, b1.z, b1.w};
        float q2[4] = {b2.x, b2.y, b2.z, b2.w};
#pragma unroll
        for (int i = 0; i < 4; ++i)
#pragma unroll
          for (int j = 0; j < 4; ++j) {
            accS[i][j] += a[i] * p[j];
            accH[i][j] += a[i] * q2[j];
          }
      }
    }
    float* Spart = ws + OFF_SPART;
    float* Hpart = ws + OFF_HPART;
#pragma unroll
    for (int i = 0; i < 4; ++i) {
      int row = ty * 4 + i;
      size_t base = ((size_t)ks * 64 + row) * 1000;
      int n = n0 + tx * 4;
      if (n + 3 < 1000) {
        *(float4*)(Spart + base + n) = make_float4(accS[i][0], accS[i][1], accS[i][2], accS[i][3]);
        *(float4*)(Hpart + base + n) = make_float4(accH[i][0], accH[i][1], accH[i][2], accH[i][3]);
      } else {
        for (int j = 0; j < 4; ++j)
          if (n + j < 1000) { Spart[base + n + j] = accS[i][j]; Hpart[base + n + j] = accH[i][j]; }
      }
    }
  } else if (bx < 512) {
    int b2i = bx - 256;
    int tile = b2i & 31, ks = b2i >> 5;
    int n0 = tile * 64;
    float acc[4][4] = {{0.f}};
    for (int kc = 0; kc < 256; kc += KB) {
      int k0 = ks * 256 + kc;
      __syncthreads();
      stage_bt(x, FF, 0, BB, k0, FF, As, t);
      stage_bt(wsel, FF, n0, FF, k0, FF, B1s, t);
      __syncthreads();
#pragma unroll 8
      for (int kk = 0; kk < KB; ++kk) {
        float4 av = *(const float4*)(As + kk * 64 + ty * 4);
        float4 b1 = *(const float4*)(B1s + kk * 64 + tx * 4);
        float a[4] = {av.x, av.y, av.z, av.w};
        float p[4] = {b1.x, b1.y, b1.z, b1.w};
#pragma unroll
        for (int i = 0; i < 4; ++i)
#pragma unroll
          for (int j = 0; j < 4; ++j) acc[i][j] += a[i] * p[j];
      }
    }
    float* selp = ws + OFF_SELP;
#pragma unroll
    for (int i = 0; i < 4; ++i) {
      int row = ty * 4 + i;
      size_t base = ((size_t)ks * 64 + row) * 2048;
      int n = n0 + tx * 4;
      *(float4*)(selp + base + n) = make_float4(acc[i][0], acc[i][1], acc[i][2], acc[i][3]);
    }
  } else {
    int nb = bx - 512;
    int w = t >> 6, lane = t & 63;
    int r = nb * 4 + w;  // 0..2063
    const float* src;
    if (r < 1000) src = cent + (size_t)r * FF;
    else if (r < 2000) src = wcos + (size_t)(r - 1000) * FF;
    else src = x + (size_t)(r - 2000) * FF;
    float s = 0.f;
#pragma unroll
    for (int i = 0; i < 8; ++i) {
      float4 v = *(const float4*)(src + i * 256 + lane * 4);
      s += v.x * v.x + v.y * v.y + v.z * v.z + v.w * v.w;
    }
#pragma unroll
    for (int off = 32; off > 0; off >>= 1) s += __shfl_down(s, off, 64);
    if (lane == 0) {
      if (r < 1000) ws[OFF_CN2 + r] = s;
      else if (r < 2000) ws[OFF_WINV + (r - 1000)] = 1.f / sqrtf(s);
      else ws[OFF_XN2 + (r - 2000)] = s;
    }
  }
}

// Phase 2: per-row (b) min-dist + softmax -> V, reach
__global__ __launch_bounds__(256) void k_softmax(const float* __restrict__ bhall,
                                                 float* __restrict__ ws) {
  int b = blockIdx.x, t = threadIdx.x;
  const float* Spart = ws + OFF_SPART;
  const float* Hpart = ws + OFF_HPART;
  __shared__ float hrow[1000];
  __shared__ float red[256];
  float xn = ws[OFF_XN2 + b];
  float lmin = 3.0e38f, lmax = -3.0e38f;
  for (int c = t; c < 1000; c += 256) {
    float S = 0.f, H = 0.f;
#pragma unroll
    for (int ks = 0; ks < 16; ++ks) {
      S += Spart[(size_t)ks * 64000 + b * 1000 + c];
      H += Hpart[(size_t)ks * 64000 + b * 1000 + c];
    }
    H += bhall[c];
    hrow[c] = H;
    float d2 = xn - 2.f * S + ws[OFF_CN2 + c];
    lmin = fminf(lmin, d2);
    lmax = fmaxf(lmax, H);
  }
  red[t] = lmin; __syncthreads();
  for (int s = 128; s > 0; s >>= 1) { if (t < s) red[t] = fminf(red[t], red[t + s]); __syncthreads(); }
  float bmin = red[0]; __syncthreads();
  red[t] = lmax; __syncthreads();
  for (int s = 128; s > 0; s >>= 1) { if (t < s) red[t] = fmaxf(red[t], red[t + s]); __syncthreads(); }
  float bmax = red[0]; __syncthreads();
  float lsum = 0.f;
  for (int c = t; c < 1000; c += 256) {
    float e = expf(hrow[c] - bmax);
    hrow[c] = e;
    lsum += e;
  }
  red[t] = lsum; __syncthreads();
  for (int s = 128; s > 0; s >>= 1) { if (t < s) red[t] += red[t + s]; __syncthreads(); }
  float inv = 1.f / red[0];
  float* V = ws + OFF_V;
  for (int c = t; c < 1000; c += 256) V[b * 1000 + c] = hrow[c] * inv;
  if (t == 0) ws[OFF_REACH + b] = 10.f / sqrtf(bmin);
}

// Phase 3: mem = V @ cent  (K=1000, N=2048), 32 tiles x 8 ksplits (chunk 128)
__global__ __launch_bounds__(256) void k_mem(const float* __restrict__ cent,
                                             float* __restrict__ ws) {
  __shared__ float As[KB * 64];
  __shared__ float Bs[KB * 64];
  int bx = blockIdx.x, t = threadIdx.x;
  int tile = bx & 31, ks = bx >> 5;
  int n0 = tile * 64;
  int tx = t & 15, ty = t >> 4;
  const float* V = ws + OFF_V;
  float acc[4][4] = {{0.f}};
  for (int kc = 0; kc < 128; kc += KB) {
    int k0 = ks * 128 + kc;
    __syncthreads();
    stage_bt(V, 1000, 0, BB, k0, 1000, As, t);
    stage_bn(cent, FF, k0, 1000, n0, Bs, t);
    __syncthreads();
#pragma unroll 8
    for (int kk = 0; kk < KB; ++kk) {
      float4 av = *(const float4*)(As + kk * 64 + ty * 4);
      float4 bv = *(const float4*)(Bs + kk * 64 + tx * 4);
      float a[4] = {av.x, av.y, av.z, av.w};
      float p[4] = {bv.x, bv.y, bv.z, bv.w};
#pragma unroll
      for (int i = 0; i < 4; ++i)
#pragma unroll
        for (int j = 0; j < 4; ++j) acc[i][j] += a[i] * p[j];
    }
  }
  float* memp = ws + OFF_MEMP;
#pragma unroll
  for (int i = 0; i < 4; ++i) {
    size_t base = ((size_t)ks * 64 + ty * 4 + i) * 2048;
    int n = n0 + tx * 4;
    *(float4*)(memp + base + n) = make_float4(acc[i][0], acc[i][1], acc[i][2], acc[i][3]);
  }
}

// Phase 4: reduce sel/mem partials, tanh, infused & direct outputs, feat + norm
__global__ __launch_bounds__(256) void k_fuse(const float* __restrict__ x,
                                              const float* __restrict__ bsel,
                                              float* __restrict__ ws, float* __restrict__ out) {
  int b = blockIdx.x, t = threadIdx.x;
  const float* selp = ws + OFF_SELP;
  const float* memp = ws + OFF_MEMP;
  float rch = ws[OFF_REACH + b];
  __shared__ float red[256];
  float nrm2 = 0.f;
  float* feat = ws + OFF_FEAT;
  for (int f = t; f < 2048; f += 256) {
    float sp = bsel[f], mm = 0.f;
#pragma unroll
    for (int ks = 0; ks < 8; ++ks) {
      sp += selp[(size_t)ks * 131072 + b * 2048 + f];
      mm += memp[(size_t)ks * 131072 + b * 2048 + f];
    }
    float sel = tanhf(sp);
    float inf = sel * mm;
    float xv = x[b * 2048 + f];
    float ft = rch * (xv + inf);
    out[64000 + b * 2048 + f] = xv;          // direct_feature
    out[195072 + b * 2048 + f] = inf;        // infused_feature
    feat[b * 2048 + f] = ft;
    nrm2 += ft * ft;
  }
  red[t] = nrm2; __syncthreads();
  for (int s = 128; s > 0; s >>= 1) { if (t < s) red[t] += red[t + s]; __syncthreads(); }
  if (t == 0) ws[OFF_SFAC + b] = 16.f / (1.f + sqrtf(red[0]));
}

// Phase 5: logits_pre = feat @ W_cos^T (K=2048, N=1000), 16 tiles x 16 ksplits (chunk 128)
__global__ __launch_bounds__(256) void k_loggemm(const float* __restrict__ wcos,
                                                 float* __restrict__ ws) {
  __shared__ float As[KB * 64];
  __shared__ float Bs[KB * 64];
  int bx = blockIdx.x, t = threadIdx.x;
  int tile = bx & 15, ks = bx >> 4;
  int n0 = tile * 64;
  int tx = t & 15, ty = t >> 4;
  const float* feat = ws + OFF_FEAT;
  float acc[4][4] = {{0.f}};
  for (int kc = 0; kc < 128; kc += KB) {
    int k0 = ks * 128 + kc;
    __syncthreads();
    stage_bt(feat, FF, 0, BB, k0, FF, As, t);
    stage_bt(wcos, FF, n0, CC, k0, FF, Bs, t);
    __syncthreads();
#pragma unroll 8
    for (int kk = 0; kk < KB; ++kk) {
      float4 av = *(const float4*)(As + kk * 64 + ty * 4);
      float4 bv = *(const float4*)(Bs + kk * 64 + tx * 4);
      float a[4] = {av.x, av.y, av.z, av.w};
      float p[4] = {bv.x, bv.y, bv.z, bv.w};
#pragma unroll
      for (int i = 0; i < 4; ++i)
#pragma unroll
        for (int j = 0; j < 4; ++j) acc[i][j] += a[i] * p[j];
    }
  }
  float* logp = ws + OFF_LOGP;
#pragma unroll
  for (int i = 0; i < 4; ++i) {
    size_t base = ((size_t)ks * 64 + ty * 4 + i) * 1000;
    int n = n0 + tx * 4;
    if (n + 3 < 1000) {
      *(float4*)(logp + base + n) = make_float4(acc[i][0], acc[i][1], acc[i][2], acc[i][3]);
    } else {
      for (int j = 0; j < 4; ++j)
        if (n + j < 1000) logp[base + n + j] = acc[i][j];
    }
  }
}

// Phase 6: reduce logits partials, apply cos-norm scales
__global__ __launch_bounds__(256) void k_final(float* __restrict__ ws, float* __restrict__ out) {
  int idx = blockIdx.x * 256 + threadIdx.x;
  if (idx >= 64000) return;
  const float* logp = ws + OFF_LOGP;
  float s = 0.f;
#pragma unroll
  for (int ks = 0; ks < 16; ++ks) s += logp[(size_t)ks * 64000 + idx];
  int b = idx / 1000;
  int c = idx - b * 1000;
  out[idx] = s * ws[OFF_SFAC + b] * ws[OFF_WINV + c];
}

extern "C" void kernel_launch(void* const* d_in, const int* in_sizes, int n_in,
                              void* d_out, int out_size, void* d_ws, size_t ws_size,
                              hipStream_t stream) {
  const float* x     = (const float*)d_in[0];
  const float* cent  = (const float*)d_in[1];
  const float* whall = (const float*)d_in[2];
  const float* bhall = (const float*)d_in[3];
  const float* wsel  = (const float*)d_in[4];
  const float* bsel  = (const float*)d_in[5];
  const float* wcos  = (const float*)d_in[6];
  float* out = (float*)d_out;
  float* ws  = (float*)d_ws;

  hipLaunchKernelGGL(k_phase1, dim3(1028), dim3(256), 0, stream, x, cent, whall, wsel, wcos, ws);
  hipLaunchKernelGGL(k_softmax, dim3(64), dim3(256), 0, stream, bhall, ws);
  hipLaunchKernelGGL(k_mem, dim3(256), dim3(256), 0, stream, cent, ws);
  hipLaunchKernelGGL(k_fuse, dim3(64), dim3(256), 0, stream, x, bsel, ws, out);
  hipLaunchKernelGGL(k_loggemm, dim3(256), dim3(256), 0, stream, wcos, ws);
  hipLaunchKernelGGL(k_final, dim3(250), dim3(256), 0, stream, ws, out);
}

// Round 2
// 144.445 us; speedup vs baseline: 1.0275x; 1.0275x over previous
//
#include <hip/hip_runtime.h>
#include <math.h>

#define FF 2048

typedef __attribute__((ext_vector_type(8))) short short8;
typedef __attribute__((ext_vector_type(4))) float floatx4;

// ws layout (float offsets), 8 K-splits everywhere
#define OFF_SPART 0              // [8][64][1000]
#define OFF_HPART 512000         // [8][64][1000]
#define OFF_SELP  1024000        // [8][64][2048]
#define OFF_MEMP  2072576        // [8][64][2048]
#define OFF_LOGP  3121152        // [8][64][1000]
#define OFF_V     3633152        // [64][1000]
#define OFF_FEAT  3697152        // [64][2048]
#define OFF_CN2   3828224        // [1000]
#define OFF_WINV  3829224        // [1000]
#define OFF_XN2   3830224        // [64]
#define OFF_REACH 3830288        // [64]
#define OFF_SFAC  3830352        // [64]

#define TP 40   // LDS tile pitch in shorts (32 data + 8 pad) -> 80 B rows, 16B-aligned, conflict-free b128 frags

// truncation-based fp32 -> bf16 hi/lo split (4 VALU ops)
__device__ __forceinline__ void split2(float f, ushort& h, ushort& l) {
  unsigned u = __float_as_uint(f);
  float r = f - __uint_as_float(u & 0xffff0000u);
  h = (ushort)(u >> 16);
  l = (ushort)(__float_as_uint(r) >> 16);
}

// Stage 64 rows x 32 k of row-major-K matrix into hi/lo bf16 LDS tiles [64][TP].
// Zero-pads rows >= nrows and k >= kmax.
__device__ __forceinline__ void stage_bt_bf(const float* __restrict__ M, int ldK, int rowBase,
                                            int nrows, int k0, int kmax,
                                            ushort* __restrict__ hi, ushort* __restrict__ lo, int t) {
  int r = t >> 2, q = t & 3;
  int grow = rowBase + r;
  bool rok = grow < nrows;
  const float* src = M + (size_t)grow * ldK + k0 + q * 8;
#pragma unroll
  for (int h = 0; h < 2; ++h) {
    int kb = k0 + q * 8 + h * 4;
    float4 v = make_float4(0.f, 0.f, 0.f, 0.f);
    if (rok) {
      if (kb + 3 < kmax) {
        v = *(const float4*)(src + h * 4);
      } else {
#pragma unroll
        for (int j = 0; j < 4; ++j)
          if (kb + j < kmax) ((float*)&v)[j] = src[h * 4 + j];
      }
    }
    ushort4 hv, lv;
    split2(v.x, hv.x, lv.x); split2(v.y, hv.y, lv.y);
    split2(v.z, hv.z, lv.z); split2(v.w, hv.w, lv.w);
    int base = r * TP + q * 8 + h * 4;
    *(ushort4*)(hi + base) = hv;
    *(ushort4*)(lo + base) = lv;
  }
}

// Stage 32 k-rows x 64 n-cols of row-major-N matrix (B[k][n]) into hi/lo LDS tiles [n][k] (transposed).
__device__ __forceinline__ void stage_tr_bf(const float* __restrict__ M, int ldN, int k0, int kmax,
                                            int n0, ushort* __restrict__ hi, ushort* __restrict__ lo, int t) {
  int kk = t >> 3, c8 = (t & 7) * 8;
  int gk = k0 + kk;
  const float* src = M + (size_t)gk * ldN + n0 + c8;
  float4 v0 = make_float4(0.f, 0.f, 0.f, 0.f), v1 = v0;
  if (gk < kmax) { v0 = *(const float4*)src; v1 = *(const float4*)(src + 4); }
#pragma unroll
  for (int j = 0; j < 8; ++j) {
    float f = (j < 4) ? ((float*)&v0)[j] : ((float*)&v1)[j - 4];
    ushort h, l;
    split2(f, h, l);
    hi[(c8 + j) * TP + kk] = h;
    lo[(c8 + j) * TP + kk] = l;
  }
}

#define MFMA(a, b, c) __builtin_amdgcn_mfma_f32_16x16x32_bf16(a, b, c, 0, 0, 0)

// Phase 1: blocks 0..127  : dual GEMM S=x@cent^T, H=x@whall^T (16 tiles x 8 splits, slab 256)
//          blocks 128..383: selpre = x@wsel^T                 (32 tiles x 8 splits, slab 256)
//          blocks 384..899: row norms (cn2, winv, xn2)
__global__ __launch_bounds__(256) void k_phase1(
    const float* __restrict__ x, const float* __restrict__ cent,
    const float* __restrict__ whall, const float* __restrict__ wsel,
    const float* __restrict__ wcos, float* __restrict__ ws) {
  __shared__ ushort u_lds[6 * 64 * TP];
  ushort* Ah  = u_lds;
  ushort* Al  = u_lds + 64 * TP;
  ushort* B1h = u_lds + 2 * 64 * TP;
  ushort* B1l = u_lds + 3 * 64 * TP;
  ushort* B2h = u_lds + 4 * 64 * TP;
  ushort* B2l = u_lds + 5 * 64 * TP;
  int bx = blockIdx.x, t = threadIdx.x;
  int ln15 = t & 15;
  int lq = (t >> 4) & 3;        // lane>>4 within wave
  int q8 = lq * 8;
  int w = t >> 6;
  int mh = w & 1, nh = w >> 1;

  if (bx < 128) {
    int tile = bx & 15, ks = bx >> 4;
    int n0 = tile * 64;
    floatx4 accS[2][2], accH[2][2];
#pragma unroll
    for (int i = 0; i < 2; ++i)
#pragma unroll
      for (int j = 0; j < 2; ++j) { accS[i][j] = (floatx4){0.f,0.f,0.f,0.f}; accH[i][j] = (floatx4){0.f,0.f,0.f,0.f}; }
    for (int kc = 0; kc < 8; ++kc) {
      int k0 = ks * 256 + kc * 32;
      __syncthreads();
      stage_bt_bf(x,     FF, 0,  64,   k0, FF, Ah,  Al,  t);
      stage_bt_bf(cent,  FF, n0, 1000, k0, FF, B1h, B1l, t);
      stage_bt_bf(whall, FF, n0, 1000, k0, FF, B2h, B2l, t);
      __syncthreads();
      short8 ah[2], al[2];
#pragma unroll
      for (int i = 0; i < 2; ++i) {
        int row = (mh * 2 + i) * 16 + ln15;
        ah[i] = *(const short8*)(Ah + row * TP + q8);
        al[i] = *(const short8*)(Al + row * TP + q8);
      }
#pragma unroll
      for (int j = 0; j < 2; ++j) {
        int brow = (nh * 2 + j) * 16 + ln15;
        short8 b1h = *(const short8*)(B1h + brow * TP + q8);
        short8 b1l = *(const short8*)(B1l + brow * TP + q8);
        short8 b2h = *(const short8*)(B2h + brow * TP + q8);
        short8 b2l = *(const short8*)(B2l + brow * TP + q8);
#pragma unroll
        for (int i = 0; i < 2; ++i) {
          accS[i][j] = MFMA(ah[i], b1h, accS[i][j]);
          accS[i][j] = MFMA(ah[i], b1l, accS[i][j]);
          accS[i][j] = MFMA(al[i], b1h, accS[i][j]);
          accH[i][j] = MFMA(ah[i], b2h, accH[i][j]);
          accH[i][j] = MFMA(ah[i], b2l, accH[i][j]);
          accH[i][j] = MFMA(al[i], b2h, accH[i][j]);
        }
      }
    }
    float* Spart = ws + OFF_SPART + (size_t)ks * 64000;
    float* Hpart = ws + OFF_HPART + (size_t)ks * 64000;
#pragma unroll
    for (int i = 0; i < 2; ++i)
#pragma unroll
      for (int j = 0; j < 2; ++j) {
        int gn = n0 + (nh * 2 + j) * 16 + ln15;
        if (gn < 1000) {
#pragma unroll
          for (int r = 0; r < 4; ++r) {
            int gm = (mh * 2 + i) * 16 + lq * 4 + r;
            Spart[gm * 1000 + gn] = accS[i][j][r];
            Hpart[gm * 1000 + gn] = accH[i][j][r];
          }
        }
      }
  } else if (bx < 384) {
    int b2 = bx - 128;
    int tile = b2 & 31, ks = b2 >> 5;
    int n0 = tile * 64;
    floatx4 acc[2][2];
#pragma unroll
    for (int i = 0; i < 2; ++i)
#pragma unroll
      for (int j = 0; j < 2; ++j) acc[i][j] = (floatx4){0.f,0.f,0.f,0.f};
    for (int kc = 0; kc < 8; ++kc) {
      int k0 = ks * 256 + kc * 32;
      __syncthreads();
      stage_bt_bf(x,    FF, 0,  64,  k0, FF, Ah,  Al,  t);
      stage_bt_bf(wsel, FF, n0, FF,  k0, FF, B1h, B1l, t);
      __syncthreads();
      short8 ah[2], al[2];
#pragma unroll
      for (int i = 0; i < 2; ++i) {
        int row = (mh * 2 + i) * 16 + ln15;
        ah[i] = *(const short8*)(Ah + row * TP + q8);
        al[i] = *(const short8*)(Al + row * TP + q8);
      }
#pragma unroll
      for (int j = 0; j < 2; ++j) {
        int brow = (nh * 2 + j) * 16 + ln15;
        short8 bh = *(const short8*)(B1h + brow * TP + q8);
        short8 bl = *(const short8*)(B1l + brow * TP + q8);
#pragma unroll
        for (int i = 0; i < 2; ++i) {
          acc[i][j] = MFMA(ah[i], bh, acc[i][j]);
          acc[i][j] = MFMA(ah[i], bl, acc[i][j]);
          acc[i][j] = MFMA(al[i], bh, acc[i][j]);
        }
      }
    }
    float* selp = ws + OFF_SELP + (size_t)ks * 131072;
#pragma unroll
    for (int i = 0; i < 2; ++i)
#pragma unroll
      for (int j = 0; j < 2; ++j) {
        int gn = n0 + (nh * 2 + j) * 16 + ln15;
#pragma unroll
        for (int r = 0; r < 4; ++r) {
          int gm = (mh * 2 + i) * 16 + lq * 4 + r;
          selp[gm * 2048 + gn] = acc[i][j][r];
        }
      }
  } else {
    int nb = bx - 384;
    int lane = t & 63;
    int r = nb * 4 + w;  // 0..2063
    const float* src;
    if (r < 1000) src = cent + (size_t)r * FF;
    else if (r < 2000) src = wcos + (size_t)(r - 1000) * FF;
    else src = x + (size_t)(r - 2000) * FF;
    float s = 0.f;
#pragma unroll
    for (int i = 0; i < 8; ++i) {
      float4 v = *(const float4*)(src + i * 256 + lane * 4);
      s += v.x * v.x + v.y * v.y + v.z * v.z + v.w * v.w;
    }
#pragma unroll
    for (int off = 32; off > 0; off >>= 1) s += __shfl_down(s, off, 64);
    if (lane == 0) {
      if (r < 1000) ws[OFF_CN2 + r] = s;
      else if (r < 2000) ws[OFF_WINV + (r - 1000)] = 1.f / sqrtf(s);
      else ws[OFF_XN2 + (r - 2000)] = s;
    }
  }
}

// Phase 2: per-row min-dist + softmax -> V, reach
__global__ __launch_bounds__(256) void k_softmax(const float* __restrict__ bhall,
                                                 float* __restrict__ ws) {
  int b = blockIdx.x, t = threadIdx.x;
  const float* Spart = ws + OFF_SPART;
  const float* Hpart = ws + OFF_HPART;
  __shared__ float hrow[1000];
  __shared__ float red[256];
  float xn = ws[OFF_XN2 + b];
  float lmin = 3.0e38f, lmax = -3.0e38f;
  for (int c = t; c < 1000; c += 256) {
    float S = 0.f, H = 0.f;
#pragma unroll
    for (int ks = 0; ks < 8; ++ks) {
      S += Spart[(size_t)ks * 64000 + b * 1000 + c];
      H += Hpart[(size_t)ks * 64000 + b * 1000 + c];
    }
    H += bhall[c];
    hrow[c] = H;
    float d2 = xn - 2.f * S + ws[OFF_CN2 + c];
    lmin = fminf(lmin, d2);
    lmax = fmaxf(lmax, H);
  }
  red[t] = lmin; __syncthreads();
  for (int s = 128; s > 0; s >>= 1) { if (t < s) red[t] = fminf(red[t], red[t + s]); __syncthreads(); }
  float bmin = red[0]; __syncthreads();
  red[t] = lmax; __syncthreads();
  for (int s = 128; s > 0; s >>= 1) { if (t < s) red[t] = fmaxf(red[t], red[t + s]); __syncthreads(); }
  float bmax = red[0]; __syncthreads();
  float lsum = 0.f;
  for (int c = t; c < 1000; c += 256) {
    float e = expf(hrow[c] - bmax);
    hrow[c] = e;
    lsum += e;
  }
  red[t] = lsum; __syncthreads();
  for (int s = 128; s > 0; s >>= 1) { if (t < s) red[t] += red[t + s]; __syncthreads(); }
  float inv = 1.f / red[0];
  float* V = ws + OFF_V;
  for (int c = t; c < 1000; c += 256) V[b * 1000 + c] = hrow[c] * inv;
  if (t == 0) ws[OFF_REACH + b] = 10.f / sqrtf(bmin);
}

// Phase 3: mem = V @ cent (K=1000, N=2048), 32 tiles x 8 splits (slab 128)
__global__ __launch_bounds__(256) void k_mem(const float* __restrict__ cent,
                                             float* __restrict__ ws) {
  __shared__ ushort u_lds[4 * 64 * TP];
  ushort* Ah = u_lds;
  ushort* Al = u_lds + 64 * TP;
  ushort* Bh = u_lds + 2 * 64 * TP;
  ushort* Bl = u_lds + 3 * 64 * TP;
  int bx = blockIdx.x, t = threadIdx.x;
  int tile = bx & 31, ks = bx >> 5;
  int n0 = tile * 64;
  int ln15 = t & 15, lq = (t >> 4) & 3, q8 = lq * 8;
  int w = t >> 6, mh = w & 1, nh = w >> 1;
  const float* V = ws + OFF_V;
  floatx4 acc[2][2];
#pragma unroll
  for (int i = 0; i < 2; ++i)
#pragma unroll
    for (int j = 0; j < 2; ++j) acc[i][j] = (floatx4){0.f,0.f,0.f,0.f};
  for (int kc = 0; kc < 4; ++kc) {
    int k0 = ks * 128 + kc * 32;
    __syncthreads();
    stage_bt_bf(V, 1000, 0, 64, k0, 1000, Ah, Al, t);
    stage_tr_bf(cent, FF, k0, 1000, n0, Bh, Bl, t);
    __syncthreads();
    short8 ah[2], al[2];
#pragma unroll
    for (int i = 0; i < 2; ++i) {
      int row = (mh * 2 + i) * 16 + ln15;
      ah[i] = *(const short8*)(Ah + row * TP + q8);
      al[i] = *(const short8*)(Al + row * TP + q8);
    }
#pragma unroll
    for (int j = 0; j < 2; ++j) {
      int brow = (nh * 2 + j) * 16 + ln15;
      short8 bh = *(const short8*)(Bh + brow * TP + q8);
      short8 bl = *(const short8*)(Bl + brow * TP + q8);
#pragma unroll
      for (int i = 0; i < 2; ++i) {
        acc[i][j] = MFMA(ah[i], bh, acc[i][j]);
        acc[i][j] = MFMA(ah[i], bl, acc[i][j]);
        acc[i][j] = MFMA(al[i], bh, acc[i][j]);
      }
    }
  }
  float* memp = ws + OFF_MEMP + (size_t)ks * 131072;
#pragma unroll
  for (int i = 0; i < 2; ++i)
#pragma unroll
    for (int j = 0; j < 2; ++j) {
      int gn = n0 + (nh * 2 + j) * 16 + ln15;
#pragma unroll
      for (int r = 0; r < 4; ++r) {
        int gm = (mh * 2 + i) * 16 + lq * 4 + r;
        memp[gm * 2048 + gn] = acc[i][j][r];
      }
    }
}

// Phase 4: reduce sel/mem partials, tanh, infused & direct outputs, feat + norm
__global__ __launch_bounds__(256) void k_fuse(const float* __restrict__ x,
                                              const float* __restrict__ bsel,
                                              float* __restrict__ ws, float* __restrict__ out) {
  int b = blockIdx.x, t = threadIdx.x;
  const float* selp = ws + OFF_SELP;
  const float* memp = ws + OFF_MEMP;
  float rch = ws[OFF_REACH + b];
  __shared__ float red[256];
  float nrm2 = 0.f;
  float* feat = ws + OFF_FEAT;
  for (int f = t; f < 2048; f += 256) {
    float sp = bsel[f], mm = 0.f;
#pragma unroll
    for (int ks = 0; ks < 8; ++ks) {
      sp += selp[(size_t)ks * 131072 + b * 2048 + f];
      mm += memp[(size_t)ks * 131072 + b * 2048 + f];
    }
    float sel = tanhf(sp);
    float inf = sel * mm;
    float xv = x[b * 2048 + f];
    float ft = rch * (xv + inf);
    out[64000 + b * 2048 + f] = xv;          // direct_feature
    out[195072 + b * 2048 + f] = inf;        // infused_feature
    feat[b * 2048 + f] = ft;
    nrm2 += ft * ft;
  }
  red[t] = nrm2; __syncthreads();
  for (int s = 128; s > 0; s >>= 1) { if (t < s) red[t] += red[t + s]; __syncthreads(); }
  if (t == 0) ws[OFF_SFAC + b] = 16.f / (1.f + sqrtf(red[0]));
}

// Phase 5: logp = feat @ wcos^T (K=2048, N=1000), 16 tiles x 8 splits (slab 256)
__global__ __launch_bounds__(256) void k_loggemm(const float* __restrict__ wcos,
                                                 float* __restrict__ ws) {
  __shared__ ushort u_lds[4 * 64 * TP];
  ushort* Ah = u_lds;
  ushort* Al = u_lds + 64 * TP;
  ushort* Bh = u_lds + 2 * 64 * TP;
  ushort* Bl = u_lds + 3 * 64 * TP;
  int bx = blockIdx.x, t = threadIdx.x;
  int tile = bx & 15, ks = bx >> 4;
  int n0 = tile * 64;
  int ln15 = t & 15, lq = (t >> 4) & 3, q8 = lq * 8;
  int w = t >> 6, mh = w & 1, nh = w >> 1;
  const float* feat = ws + OFF_FEAT;
  floatx4 acc[2][2];
#pragma unroll
  for (int i = 0; i < 2; ++i)
#pragma unroll
    for (int j = 0; j < 2; ++j) acc[i][j] = (floatx4){0.f,0.f,0.f,0.f};
  for (int kc = 0; kc < 8; ++kc) {
    int k0 = ks * 256 + kc * 32;
    __syncthreads();
    stage_bt_bf(feat, FF, 0,  64,   k0, FF, Ah, Al, t);
    stage_bt_bf(wcos, FF, n0, 1000, k0, FF, Bh, Bl, t);
    __syncthreads();
    short8 ah[2], al[2];
#pragma unroll
    for (int i = 0; i < 2; ++i) {
      int row = (mh * 2 + i) * 16 + ln15;
      ah[i] = *(const short8*)(Ah + row * TP + q8);
      al[i] = *(const short8*)(Al + row * TP + q8);
    }
#pragma unroll
    for (int j = 0; j < 2; ++j) {
      int brow = (nh * 2 + j) * 16 + ln15;
      short8 bh = *(const short8*)(Bh + brow * TP + q8);
      short8 bl = *(const short8*)(Bl + brow * TP + q8);
#pragma unroll
      for (int i = 0; i < 2; ++i) {
        acc[i][j] = MFMA(ah[i], bh, acc[i][j]);
        acc[i][j] = MFMA(ah[i], bl, acc[i][j]);
        acc[i][j] = MFMA(al[i], bh, acc[i][j]);
      }
    }
  }
  float* logp = ws + OFF_LOGP + (size_t)ks * 64000;
#pragma unroll
  for (int i = 0; i < 2; ++i)
#pragma unroll
    for (int j = 0; j < 2; ++j) {
      int gn = n0 + (nh * 2 + j) * 16 + ln15;
      if (gn < 1000) {
#pragma unroll
        for (int r = 0; r < 4; ++r) {
          int gm = (mh * 2 + i) * 16 + lq * 4 + r;
          logp[gm * 1000 + gn] = acc[i][j][r];
        }
      }
    }
}

// Phase 6: reduce logits partials, apply cos-norm scales
__global__ __launch_bounds__(256) void k_final(float* __restrict__ ws, float* __restrict__ out) {
  int idx = blockIdx.x * 256 + threadIdx.x;
  if (idx >= 64000) return;
  const float* logp = ws + OFF_LOGP;
  float s = 0.f;
#pragma unroll
  for (int ks = 0; ks < 8; ++ks) s += logp[(size_t)ks * 64000 + idx];
  int b = idx / 1000;
  int c = idx - b * 1000;
  out[idx] = s * ws[OFF_SFAC + b] * ws[OFF_WINV + c];
}

extern "C" void kernel_launch(void* const* d_in, const int* in_sizes, int n_in,
                              void* d_out, int out_size, void* d_ws, size_t ws_size,
                              hipStream_t stream) {
  const float* x     = (const float*)d_in[0];
  const float* cent  = (const float*)d_in[1];
  const float* whall = (const float*)d_in[2];
  const float* bhall = (const float*)d_in[3];
  const float* wsel  = (const float*)d_in[4];
  const float* bsel  = (const float*)d_in[5];
  const float* wcos  = (const float*)d_in[6];
  float* out = (float*)d_out;
  float* ws  = (float*)d_ws;

  hipLaunchKernelGGL(k_phase1, dim3(900), dim3(256), 0, stream, x, cent, whall, wsel, wcos, ws);
  hipLaunchKernelGGL(k_softmax, dim3(64), dim3(256), 0, stream, bhall, ws);
  hipLaunchKernelGGL(k_mem, dim3(256), dim3(256), 0, stream, cent, ws);
  hipLaunchKernelGGL(k_fuse, dim3(64), dim3(256), 0, stream, x, bsel, ws, out);
  hipLaunchKernelGGL(k_loggemm, dim3(128), dim3(256), 0, stream, wcos, ws);
  hipLaunchKernelGGL(k_final, dim3(250), dim3(256), 0, stream, ws, out);
}